// Round 9
// baseline (167.529 us; speedup 1.0000x reference)
//
#include <hip/hip_runtime.h>

#define NH 12
#define DM 768
#define HD 64
#define BB 4
#define SS 1024
#define MTOT (BB*SS)          // 4096 rows
// Q pre-scale folded with log2(e): softmax computed in exp2 domain.
#define ATT_SCALE_L2E 0.18033688011112042f   // 0.125 * log2(e)
#define NEGMASK_L2E  (-5.846602e18f)         // -(3^39) * log2(e)

typedef __attribute__((ext_vector_type(8))) short short8;
typedef __attribute__((ext_vector_type(4))) float floatx4;
typedef __attribute__((ext_vector_type(4))) unsigned short ushort4v;
typedef __attribute__((ext_vector_type(2))) unsigned int uint2v;

__device__ __forceinline__ float bf2f(unsigned short u){
    union { unsigned int i; float f; } x; x.i = ((unsigned int)u) << 16; return x.f;
}
__device__ __forceinline__ unsigned short f2bf(float f){
    union { float f; unsigned int i; } x; x.f = f;
    unsigned int i = x.i;
    return (unsigned short)((i + 0x7FFFu + ((i >> 16) & 1u)) >> 16);  // RNE
}
__device__ __forceinline__ unsigned int pack_trunc(float lo, float hi){
    union { float f; unsigned int i; } a, b; a.f = lo; b.f = hi;
    return (b.i & 0xffff0000u) | (a.i >> 16);   // [hi_bf16 | lo_bf16]
}

// ---------------------------------------------------------------------------
// Kernel 0: fp32 -> bf16 conversion of X and the 4 weight matrices.
// Wq/Wk/Wv land contiguously -> usable as one packed [2304,768] matrix.
// ---------------------------------------------------------------------------
#define XQ4 (MTOT*DM/4)   // 786432 float4 groups in X
#define WQ4 (DM*DM/4)     // 147456 float4 groups per weight

__global__ __launch_bounds__(256) void convert_bf16(
    const float* __restrict__ X,
    const float* __restrict__ Wq, const float* __restrict__ Wk,
    const float* __restrict__ Wv, const float* __restrict__ Wo,
    unsigned short* __restrict__ Xb,
    unsigned short* __restrict__ Wqb, unsigned short* __restrict__ Wkb,
    unsigned short* __restrict__ Wvb, unsigned short* __restrict__ Wob)
{
    const int idx = blockIdx.x * 256 + threadIdx.x;
    const float* s; unsigned short* d; int off;
    if (idx < XQ4) { s = X; d = Xb; off = idx; }
    else {
        const int r = idx - XQ4;
        const int wsel = r / WQ4;
        off = r - wsel * WQ4;
        s = (wsel==0)?Wq:(wsel==1)?Wk:(wsel==2)?Wv:Wo;
        d = (wsel==0)?Wqb:(wsel==1)?Wkb:(wsel==2)?Wvb:Wob;
    }
    const float4 v = ((const float4*)s)[off];
    ushort4v o;
    o[0] = f2bf(v.x); o[1] = f2bf(v.y); o[2] = f2bf(v.z); o[3] = f2bf(v.w);
    ((ushort4v*)d)[off] = o;
}

// ---------------------------------------------------------------------------
// Shared GEMM machinery (R8, verified): 128x64 tile, BK=64, single-buffered
// XOR-chunk-swizzled LDS, global_load_lds 16B/lane, 4 waves in 2x2.
// ---------------------------------------------------------------------------
__device__ __forceinline__ void gemm_stage64(
    const unsigned short* __restrict__ A,
    const unsigned short* __restrict__ Bm,
    int m0, int n0, int k0, int w, int lane,
    unsigned short* __restrict__ As,          // 128*64 bf16
    unsigned short* __restrict__ Bs)          // 64*64 bf16
{
    const int rsub = lane >> 3;               // 0..7
    const int cc   = (lane & 7) ^ rsub;       // swizzled 8-elem chunk
    #pragma unroll
    for (int j = 0; j < 4; ++j) {
        const int rb = w*32 + j*8;
        __builtin_amdgcn_global_load_lds(
            (const __attribute__((address_space(1))) unsigned int*)
                (A + (size_t)(m0 + rb + rsub) * DM + k0 + cc*8),
            (__attribute__((address_space(3))) unsigned int*)(As + rb*64),
            16, 0, 0);
    }
    #pragma unroll
    for (int j = 0; j < 2; ++j) {
        const int rb = w*16 + j*8;
        __builtin_amdgcn_global_load_lds(
            (const __attribute__((address_space(1))) unsigned int*)
                (Bm + (size_t)(n0 + rb + rsub) * DM + k0 + cc*8),
            (__attribute__((address_space(3))) unsigned int*)(Bs + rb*64),
            16, 0, 0);
    }
}

__device__ __forceinline__ void gemm_compute64(
    const unsigned short* __restrict__ As,
    const unsigned short* __restrict__ Bs,
    int wr, int wc, int c, int g, floatx4 (&acc)[4][2])
{
    #pragma unroll
    for (int st = 0; st < 2; ++st) {
        const int chunk = ((g + 4*st) ^ (c & 7)) * 8;
        short8 af[4], bfr[2];
        #pragma unroll
        for (int mi = 0; mi < 4; ++mi)
            af[mi] = *(const short8*)(As + (wr*64 + mi*16 + c)*64 + chunk);
        #pragma unroll
        for (int ni = 0; ni < 2; ++ni)
            bfr[ni] = *(const short8*)(Bs + (wc*32 + ni*16 + c)*64 + chunk);
        #pragma unroll
        for (int mi = 0; mi < 4; ++mi)
            #pragma unroll
            for (int ni = 0; ni < 2; ++ni)
                acc[mi][ni] = __builtin_amdgcn_mfma_f32_16x16x32_bf16(
                    af[mi], bfr[ni], acc[mi][ni], 0, 0, 0);
    }
}

// ---------------------------------------------------------------------------
// Kernel 1: fused QKV projection vs packed W[2304,768] (R8, verified).
// Q scaled by 0.125*log2e (exp2-domain softmax downstream).
// ---------------------------------------------------------------------------
__global__ __launch_bounds__(256) void qkv_mfma(
    const unsigned short* __restrict__ Xb,     // [4096,768] bf16
    const unsigned short* __restrict__ Wqkv,   // [2304,768] bf16 packed
    const float* __restrict__ bq, const float* __restrict__ bk,
    const float* __restrict__ bv,
    unsigned short* __restrict__ qout,         // [B,H,S,HD]
    unsigned short* __restrict__ kout,         // [B,H,S,HD]
    unsigned short* __restrict__ vout)         // [B,H,HD,S]
{
    const int bx = blockIdx.x;                 // 0..35
    const int which = bx / 12;
    const int np0 = (bx % 12) * 64;
    const int n0 = bx * 64;
    const int m0 = blockIdx.y * 128;

    const float* bias = (which==0) ? bq : (which==1) ? bk : bv;
    const float scl = (which==0) ? ATT_SCALE_L2E : 1.0f;

    __shared__ unsigned short As[128*64];      // 16 KB
    __shared__ unsigned short Bs[64*64];       // 8 KB

    const int t = threadIdx.x;
    const int w = t >> 6, lane = t & 63;
    const int c = lane & 15, g = lane >> 4;
    const int wr = w >> 1, wc = w & 1;

    floatx4 acc[4][2] = {};

    for (int kt = 0; kt < 12; ++kt) {
        __syncthreads();
        gemm_stage64(Xb, Wqkv, m0, n0, kt*64, w, lane, As, Bs);
        __syncthreads();
        gemm_compute64(As, Bs, wr, wc, c, g, acc);
    }

    #pragma unroll
    for (int mi = 0; mi < 4; ++mi) {
        #pragma unroll
        for (int r = 0; r < 4; ++r) {
            const int m = m0 + wr*64 + mi*16 + g*4 + r;
            const int b = m >> 10, s = m & 1023;
            #pragma unroll
            for (int ni = 0; ni < 2; ++ni) {
                const int np = np0 + wc*32 + ni*16 + c;
                const int h = np >> 6, hd = np & 63;
                const float val = (acc[mi][ni][r] + bias[np]) * scl;
                if (which == 2)
                    vout[(((size_t)(b*NH + h))*HD + hd)*SS + s] = f2bf(val);
                else if (which == 1)
                    kout[(((size_t)(b*NH + h))*SS + s)*HD + hd] = f2bf(val);
                else
                    qout[(((size_t)(b*NH + h))*SS + s)*HD + hd] = f2bf(val);
            }
        }
    }
}

// ---------------------------------------------------------------------------
// Kernel 2: causal flash attention. 128-query blocks, 4 waves x 32 queries
// (2 q-frags/wave). K/V tiles (64 keys) staged via DMA, double-buffered,
// XOR-swizzled (R6-verified). Waves skip fully-masked tiles. Softmax in
// exp2 domain. P packed by truncation.
// ---------------------------------------------------------------------------
__device__ __forceinline__ void stage_tile(
    const unsigned short* __restrict__ Kp,
    const unsigned short* __restrict__ VTp,
    int k0, int w, int lane,
    unsigned short* __restrict__ Ks,   // 64*64 bf16
    unsigned short* __restrict__ Vs)   // 64*64 bf16
{
    const int rsub = lane >> 3;
    const int cc   = (lane & 7) ^ rsub;
    #pragma unroll
    for (int j = 0; j < 2; ++j) {
        const int r = w*16 + j*8 + rsub;
        __builtin_amdgcn_global_load_lds(
            (const __attribute__((address_space(1))) unsigned int*)
                (Kp + (size_t)(k0 + r) * HD + cc*8),
            (__attribute__((address_space(3))) unsigned int*)
                (Ks + (w*16 + j*8) * HD),
            16, 0, 0);
        __builtin_amdgcn_global_load_lds(
            (const __attribute__((address_space(1))) unsigned int*)
                (VTp + (size_t)r * SS + k0 + cc*8),
            (__attribute__((address_space(3))) unsigned int*)
                (Vs + (w*16 + j*8) * HD),
            16, 0, 0);
    }
}

__device__ __forceinline__ void attn_process_tile(
    const unsigned short* __restrict__ Ks,
    const unsigned short* __restrict__ Vs,
    const short8 (&qf)[2][2],          // [qt][st]
    int k0, int qw0, int c, int g,
    float (&m_c)[2], float (&l_c)[2], floatx4 (&Oacc)[4][2],
    unsigned short* __restrict__ Pl)   // 32*72 per wave
{
    // ---- S^T = K Q^T : A = K rows from LDS (swizzled), B = qf ----
    floatx4 S[4][2] = {};
    #pragma unroll
    for (int nf = 0; nf < 4; ++nf) {
        const int row = nf*16 + c;
        #pragma unroll
        for (int st = 0; st < 2; ++st) {
            const short8 kf = *(const short8*)(Ks + row*HD + (((g + 4*st) ^ (c & 7)) * 8));
            #pragma unroll
            for (int qt = 0; qt < 2; ++qt)
                S[nf][qt] = __builtin_amdgcn_mfma_f32_16x16x32_bf16(kf, qf[qt][st], S[nf][qt], 0, 0, 0);
        }
    }

    // ---- causal mask (wave-uniform gate; per-lane refine) ----
    if (k0 + 63 > qw0) {
        #pragma unroll
        for (int qt = 0; qt < 2; ++qt) {
            const int qg = qw0 + 16*qt + c;
            #pragma unroll
            for (int nf = 0; nf < 4; ++nf) {
                #pragma unroll
                for (int r = 0; r < 4; ++r) {
                    const int key = k0 + nf*16 + g*4 + r;
                    if (key > qg) S[nf][qt][r] += NEGMASK_L2E;
                }
            }
        }
    }

    // ---- per-lane online softmax (exp2 domain), per q-frag ----
    #pragma unroll
    for (int qt = 0; qt < 2; ++qt) {
        float mx = -INFINITY;
        #pragma unroll
        for (int nf = 0; nf < 4; ++nf)
            #pragma unroll
            for (int r = 0; r < 4; ++r) mx = fmaxf(mx, S[nf][qt][r]);
        mx = fmaxf(mx, __shfl_xor(mx, 16, 64));
        mx = fmaxf(mx, __shfl_xor(mx, 32, 64));
        const float mnew = fmaxf(m_c[qt], mx);
        const float alpha = exp2f(m_c[qt] - mnew);
        float sum = 0.0f;
        #pragma unroll
        for (int nf = 0; nf < 4; ++nf)
            #pragma unroll
            for (int r = 0; r < 4; ++r) {
                const float p = exp2f(S[nf][qt][r] - mnew);
                S[nf][qt][r] = p;
                sum += p;
            }
        sum += __shfl_xor(sum, 16, 64);
        sum += __shfl_xor(sum, 32, 64);
        l_c[qt] = l_c[qt] * alpha + sum;
        m_c[qt] = mnew;
        #pragma unroll
        for (int nf = 0; nf < 4; ++nf)
            #pragma unroll
            for (int r = 0; r < 4; ++r) Oacc[nf][qt][r] *= alpha;

        // ---- P^T C-layout -> LDS as P[q][k] (truncation pack, b64 store) ----
        #pragma unroll
        for (int nf = 0; nf < 4; ++nf) {
            uint2v u;
            u[0] = pack_trunc(S[nf][qt][0], S[nf][qt][1]);
            u[1] = pack_trunc(S[nf][qt][2], S[nf][qt][3]);
            *(uint2v*)(Pl + (16*qt + c)*72 + nf*16 + g*4) = u;
        }
    }

    // ---- O^T += V^T P : A = V rows (d) from LDS (swizzled), B = P ----
    #pragma unroll
    for (int st = 0; st < 2; ++st) {
        short8 pf[2];
        #pragma unroll
        for (int qt = 0; qt < 2; ++qt)
            pf[qt] = *(const short8*)(Pl + (16*qt + c)*72 + g*8 + 32*st);
        #pragma unroll
        for (int nf = 0; nf < 4; ++nf) {
            const int row = nf*16 + c;
            const short8 vf = *(const short8*)(Vs + row*HD + (((g + 4*st) ^ (c & 7)) * 8));
            #pragma unroll
            for (int qt = 0; qt < 2; ++qt)
                Oacc[nf][qt] = __builtin_amdgcn_mfma_f32_16x16x32_bf16(vf, pf[qt], Oacc[nf][qt], 0, 0, 0);
        }
    }
}

__global__ __launch_bounds__(256) void attn_mfma(
    const unsigned short* __restrict__ Q,   // [B,H,S,HD] bf16 (pre-scaled, exp2 domain)
    const unsigned short* __restrict__ K,   // [B,H,S,HD]
    const unsigned short* __restrict__ VT,  // [B,H,HD,S]
    unsigned short* __restrict__ O)         // [B,S,H*HD] bf16
{
    const int idx = blockIdx.x;             // 0..383
    const int bh  = idx % 48;
    const int z   = 7 - (idx / 48);         // q128-tile, LPT: big z first
    const int q0  = z * 128;

    const unsigned short* Qp  = Q  + (size_t)bh * SS * HD;
    const unsigned short* Kp  = K  + (size_t)bh * SS * HD;
    const unsigned short* VTp = VT + (size_t)bh * HD * SS;

    __shared__ unsigned short Ks[2][64*HD]; // 16 KB
    __shared__ unsigned short Vs[2][64*HD]; // 16 KB
    __shared__ unsigned short Pl[4][32*72]; // 18 KB

    const int t    = threadIdx.x;
    const int w    = t >> 6;                // wave -> queries qw0..qw0+31
    const int lane = t & 63;
    const int c    = lane & 15;
    const int g    = lane >> 4;
    const int qw0  = q0 + w*32;

    short8 qf[2][2];
    #pragma unroll
    for (int qt = 0; qt < 2; ++qt)
        #pragma unroll
        for (int st = 0; st < 2; ++st)
            qf[qt][st] = *(const short8*)(Qp + (size_t)(qw0 + 16*qt + c) * HD + g*8 + 32*st);

    floatx4 Oacc[4][2] = {};   // O^T: [d-frag nf][q-frag qt]
    float m_c[2] = {-INFINITY, -INFINITY}, l_c[2] = {0.0f, 0.0f};

    const int ntile = 2*z + 2;              // 64-key tiles covering keys <= q0+127

    stage_tile(Kp, VTp, 0, w, lane, Ks[0], Vs[0]);
    __syncthreads();

    for (int kt = 0; kt < ntile; ++kt) {
        const int cur = kt & 1;
        const int k0 = kt * 64;
        if (kt + 1 < ntile)
            stage_tile(Kp, VTp, (kt+1)*64, w, lane, Ks[cur^1], Vs[cur^1]);
        if (k0 <= qw0 + 31)                 // skip fully-masked tiles (wave-uniform)
            attn_process_tile(Ks[cur], Vs[cur], qf, k0, qw0,
                              c, g, m_c, l_c, Oacc, Pl[w]);
        if (kt + 1 < ntile)
            __syncthreads();
    }

    // ---- epilogue: normalize, write [B,S,H*HD] bf16 (8B stores) ----
    const int b = bh / NH, h = bh % NH;
    #pragma unroll
    for (int qt = 0; qt < 2; ++qt) {
        const float inv = 1.0f / l_c[qt];
        unsigned short* op = O + ((size_t)(b*SS + qw0 + 16*qt + c))*DM + h*HD;
        #pragma unroll
        for (int nf = 0; nf < 4; ++nf) {
            ushort4v o4;
            #pragma unroll
            for (int r = 0; r < 4; ++r) o4[r] = f2bf(Oacc[nf][qt][r] * inv);
            *(ushort4v*)(op + nf*16 + g*4) = o4;
        }
    }
}

// ---------------------------------------------------------------------------
// Kernel 3: output projection, 128x64 BK=64 single-buffered (R8, verified).
// ---------------------------------------------------------------------------
__global__ __launch_bounds__(256) void out_mfma(
    const unsigned short* __restrict__ A,    // [4096,768] bf16
    const unsigned short* __restrict__ Wb,   // [768,768] bf16
    const float* __restrict__ bias,
    float* __restrict__ outf)
{
    const int n0 = blockIdx.x * 64;
    const int m0 = blockIdx.y * 128;

    __shared__ unsigned short As[128*64];
    __shared__ unsigned short Bs[64*64];

    const int t = threadIdx.x;
    const int w = t >> 6, lane = t & 63;
    const int c = lane & 15, g = lane >> 4;
    const int wr = w >> 1, wc = w & 1;

    floatx4 acc[4][2] = {};

    for (int kt = 0; kt < 12; ++kt) {
        __syncthreads();
        gemm_stage64(A, Wb, m0, n0, kt*64, w, lane, As, Bs);
        __syncthreads();
        gemm_compute64(As, Bs, wr, wc, c, g, acc);
    }

    #pragma unroll
    for (int mi = 0; mi < 4; ++mi) {
        #pragma unroll
        for (int r = 0; r < 4; ++r) {
            const int m = m0 + wr*64 + mi*16 + g*4 + r;
            #pragma unroll
            for (int ni = 0; ni < 2; ++ni) {
                const int n = n0 + wc*32 + ni*16 + c;
                outf[(size_t)m * DM + n] = acc[mi][ni][r] + bias[n];
            }
        }
    }
}

// ---------------------------------------------------------------------------
extern "C" void kernel_launch(void* const* d_in, const int* in_sizes, int n_in,
                              void* d_out, int out_size, void* d_ws, size_t ws_size,
                              hipStream_t stream) {
    const float* X  = (const float*)d_in[0];
    const float* Wq = (const float*)d_in[1];
    const float* bq = (const float*)d_in[2];
    const float* Wk = (const float*)d_in[3];
    const float* bk = (const float*)d_in[4];
    const float* Wv = (const float*)d_in[5];
    const float* bv = (const float*)d_in[6];
    const float* Wo = (const float*)d_in[7];
    const float* bo = (const float*)d_in[8];
    float* out = (float*)d_out;

    const size_t elems = (size_t)MTOT * DM;       // 3,145,728
    const size_t welems = (size_t)DM * DM;        //   589,824
    unsigned short* q    = (unsigned short*)d_ws;
    unsigned short* k    = q    + elems;
    unsigned short* vt   = k    + elems;          // V transposed [B,H,HD,S]
    unsigned short* attn = vt   + elems;
    unsigned short* xb   = attn + elems;
    unsigned short* wqb  = xb   + elems;          // packed W_qkv starts here
    unsigned short* wkb  = wqb  + welems;
    unsigned short* wvb  = wkb  + welems;
    unsigned short* wob  = wvb  + welems;         // total ~36.2 MB

    convert_bf16<<<dim3((XQ4 + 4*WQ4) / 256), 256, 0, stream>>>(
        X, Wq, Wk, Wv, Wo, xb, wqb, wkb, wvb, wob);
    qkv_mfma<<<dim3(36, 32), 256, 0, stream>>>(
        xb, wqb, bq, bk, bv, q, k, vt);
    attn_mfma<<<dim3(384), 256, 0, stream>>>(q, k, vt, attn);
    out_mfma<<<dim3(12, 32), 256, 0, stream>>>(attn, wob, bo, out);
}

// Round 10
// 152.878 us; speedup vs baseline: 1.0958x; 1.0958x over previous
//
#include <hip/hip_runtime.h>

#define NH 12
#define DM 768
#define HD 64
#define BB 4
#define SS 1024
#define MTOT (BB*SS)          // 4096 rows
// Q pre-scale folded with log2(e): softmax computed in exp2 domain.
#define ATT_SCALE_L2E 0.18033688011112042f   // 0.125 * log2(e)
#define NEGMASK_L2E  (-5.846602e18f)         // -(3^39) * log2(e)

typedef __attribute__((ext_vector_type(8))) short short8;
typedef __attribute__((ext_vector_type(4))) float floatx4;
typedef __attribute__((ext_vector_type(4))) unsigned short ushort4v;
typedef __attribute__((ext_vector_type(2))) unsigned int uint2v;

__device__ __forceinline__ float bf2f(unsigned short u){
    union { unsigned int i; float f; } x; x.i = ((unsigned int)u) << 16; return x.f;
}
__device__ __forceinline__ unsigned short f2bf(float f){
    union { float f; unsigned int i; } x; x.f = f;
    unsigned int i = x.i;
    return (unsigned short)((i + 0x7FFFu + ((i >> 16) & 1u)) >> 16);  // RNE
}
__device__ __forceinline__ unsigned int pack_trunc(float lo, float hi){
    union { float f; unsigned int i; } a, b; a.f = lo; b.f = hi;
    return (b.i & 0xffff0000u) | (a.i >> 16);   // [hi_bf16 | lo_bf16]
}

// ---------------------------------------------------------------------------
// Kernel 0: fp32 -> bf16 conversion of X and the 4 weight matrices.
// Wq/Wk/Wv land contiguously -> usable as one packed [2304,768] matrix.
// ---------------------------------------------------------------------------
#define XQ4 (MTOT*DM/4)   // 786432 float4 groups in X
#define WQ4 (DM*DM/4)     // 147456 float4 groups per weight

__global__ __launch_bounds__(256) void convert_bf16(
    const float* __restrict__ X,
    const float* __restrict__ Wq, const float* __restrict__ Wk,
    const float* __restrict__ Wv, const float* __restrict__ Wo,
    unsigned short* __restrict__ Xb,
    unsigned short* __restrict__ Wqb, unsigned short* __restrict__ Wkb,
    unsigned short* __restrict__ Wvb, unsigned short* __restrict__ Wob)
{
    const int idx = blockIdx.x * 256 + threadIdx.x;
    const float* s; unsigned short* d; int off;
    if (idx < XQ4) { s = X; d = Xb; off = idx; }
    else {
        const int r = idx - XQ4;
        const int wsel = r / WQ4;
        off = r - wsel * WQ4;
        s = (wsel==0)?Wq:(wsel==1)?Wk:(wsel==2)?Wv:Wo;
        d = (wsel==0)?Wqb:(wsel==1)?Wkb:(wsel==2)?Wvb:Wob;
    }
    const float4 v = ((const float4*)s)[off];
    ushort4v o;
    o[0] = f2bf(v.x); o[1] = f2bf(v.y); o[2] = f2bf(v.z); o[3] = f2bf(v.w);
    ((ushort4v*)d)[off] = o;
}

// ---------------------------------------------------------------------------
// Shared GEMM machinery (R8, verified): 128x64 tile, BK=64, single-buffered
// XOR-chunk-swizzled LDS, global_load_lds 16B/lane, 4 waves in 2x2.
// ---------------------------------------------------------------------------
__device__ __forceinline__ void gemm_stage64(
    const unsigned short* __restrict__ A,
    const unsigned short* __restrict__ Bm,
    int m0, int n0, int k0, int w, int lane,
    unsigned short* __restrict__ As,          // 128*64 bf16
    unsigned short* __restrict__ Bs)          // 64*64 bf16
{
    const int rsub = lane >> 3;               // 0..7
    const int cc   = (lane & 7) ^ rsub;       // swizzled 8-elem chunk
    #pragma unroll
    for (int j = 0; j < 4; ++j) {
        const int rb = w*32 + j*8;
        __builtin_amdgcn_global_load_lds(
            (const __attribute__((address_space(1))) unsigned int*)
                (A + (size_t)(m0 + rb + rsub) * DM + k0 + cc*8),
            (__attribute__((address_space(3))) unsigned int*)(As + rb*64),
            16, 0, 0);
    }
    #pragma unroll
    for (int j = 0; j < 2; ++j) {
        const int rb = w*16 + j*8;
        __builtin_amdgcn_global_load_lds(
            (const __attribute__((address_space(1))) unsigned int*)
                (Bm + (size_t)(n0 + rb + rsub) * DM + k0 + cc*8),
            (__attribute__((address_space(3))) unsigned int*)(Bs + rb*64),
            16, 0, 0);
    }
}

__device__ __forceinline__ void gemm_compute64(
    const unsigned short* __restrict__ As,
    const unsigned short* __restrict__ Bs,
    int wr, int wc, int c, int g, floatx4 (&acc)[4][2])
{
    #pragma unroll
    for (int st = 0; st < 2; ++st) {
        const int chunk = ((g + 4*st) ^ (c & 7)) * 8;
        short8 af[4], bfr[2];
        #pragma unroll
        for (int mi = 0; mi < 4; ++mi)
            af[mi] = *(const short8*)(As + (wr*64 + mi*16 + c)*64 + chunk);
        #pragma unroll
        for (int ni = 0; ni < 2; ++ni)
            bfr[ni] = *(const short8*)(Bs + (wc*32 + ni*16 + c)*64 + chunk);
        #pragma unroll
        for (int mi = 0; mi < 4; ++mi)
            #pragma unroll
            for (int ni = 0; ni < 2; ++ni)
                acc[mi][ni] = __builtin_amdgcn_mfma_f32_16x16x32_bf16(
                    af[mi], bfr[ni], acc[mi][ni], 0, 0, 0);
    }
}

// ---------------------------------------------------------------------------
// Kernel 1: fused QKV projection vs packed W[2304,768] (R8, verified).
// Q scaled by 0.125*log2e (exp2-domain softmax downstream).
// ---------------------------------------------------------------------------
__global__ __launch_bounds__(256) void qkv_mfma(
    const unsigned short* __restrict__ Xb,     // [4096,768] bf16
    const unsigned short* __restrict__ Wqkv,   // [2304,768] bf16 packed
    const float* __restrict__ bq, const float* __restrict__ bk,
    const float* __restrict__ bv,
    unsigned short* __restrict__ qout,         // [B,H,S,HD]
    unsigned short* __restrict__ kout,         // [B,H,S,HD]
    unsigned short* __restrict__ vout)         // [B,H,HD,S]
{
    const int bx = blockIdx.x;                 // 0..35
    const int which = bx / 12;
    const int np0 = (bx % 12) * 64;
    const int n0 = bx * 64;
    const int m0 = blockIdx.y * 128;

    const float* bias = (which==0) ? bq : (which==1) ? bk : bv;
    const float scl = (which==0) ? ATT_SCALE_L2E : 1.0f;

    __shared__ unsigned short As[128*64];      // 16 KB
    __shared__ unsigned short Bs[64*64];       // 8 KB

    const int t = threadIdx.x;
    const int w = t >> 6, lane = t & 63;
    const int c = lane & 15, g = lane >> 4;
    const int wr = w >> 1, wc = w & 1;

    floatx4 acc[4][2] = {};

    for (int kt = 0; kt < 12; ++kt) {
        __syncthreads();
        gemm_stage64(Xb, Wqkv, m0, n0, kt*64, w, lane, As, Bs);
        __syncthreads();
        gemm_compute64(As, Bs, wr, wc, c, g, acc);
    }

    #pragma unroll
    for (int mi = 0; mi < 4; ++mi) {
        #pragma unroll
        for (int r = 0; r < 4; ++r) {
            const int m = m0 + wr*64 + mi*16 + g*4 + r;
            const int b = m >> 10, s = m & 1023;
            #pragma unroll
            for (int ni = 0; ni < 2; ++ni) {
                const int np = np0 + wc*32 + ni*16 + c;
                const int h = np >> 6, hd = np & 63;
                const float val = (acc[mi][ni][r] + bias[np]) * scl;
                if (which == 2)
                    vout[(((size_t)(b*NH + h))*HD + hd)*SS + s] = f2bf(val);
                else if (which == 1)
                    kout[(((size_t)(b*NH + h))*SS + s)*HD + hd] = f2bf(val);
                else
                    qout[(((size_t)(b*NH + h))*SS + s)*HD + hd] = f2bf(val);
            }
        }
    }
}

// ---------------------------------------------------------------------------
// Kernel 2: causal flash attention — R8/R6-verified structure (64 queries per
// block, 16/wave, 768 blocks LPT, DMA-staged double-buffered XOR-swizzled
// K/V tiles), with exp2-domain softmax and truncation-packed P.
// ---------------------------------------------------------------------------
__device__ __forceinline__ void stage_tile(
    const unsigned short* __restrict__ Kp,
    const unsigned short* __restrict__ VTp,
    int k0, int w, int lane,
    unsigned short* __restrict__ Ks,   // 64*64 bf16
    unsigned short* __restrict__ Vs)   // 64*64 bf16
{
    const int rsub = lane >> 3;
    const int cc   = (lane & 7) ^ rsub;
    #pragma unroll
    for (int j = 0; j < 2; ++j) {
        const int r = w*16 + j*8 + rsub;
        __builtin_amdgcn_global_load_lds(
            (const __attribute__((address_space(1))) unsigned int*)
                (Kp + (size_t)(k0 + r) * HD + cc*8),
            (__attribute__((address_space(3))) unsigned int*)
                (Ks + (w*16 + j*8) * HD),
            16, 0, 0);
        __builtin_amdgcn_global_load_lds(
            (const __attribute__((address_space(1))) unsigned int*)
                (VTp + (size_t)r * SS + k0 + cc*8),
            (__attribute__((address_space(3))) unsigned int*)
                (Vs + (w*16 + j*8) * HD),
            16, 0, 0);
    }
}

__device__ __forceinline__ void attn_process_tile(
    const unsigned short* __restrict__ Ks,
    const unsigned short* __restrict__ Vs,
    const short8 (&qf)[2],
    int k0, bool islast, int qg, int c, int g,
    float& m_c, float& l_c, floatx4 (&Oacc)[4],
    unsigned short* __restrict__ Pl)
{
    // ---- S^T = K Q^T : A = K rows from LDS (swizzled), B = qf ----
    floatx4 S[4] = {};
    #pragma unroll
    for (int nf = 0; nf < 4; ++nf) {
        const int row = nf*16 + c;
        #pragma unroll
        for (int st = 0; st < 2; ++st) {
            const short8 kf = *(const short8*)(Ks + row*HD + (((g + 4*st) ^ (c & 7)) * 8));
            S[nf] = __builtin_amdgcn_mfma_f32_16x16x32_bf16(kf, qf[st], S[nf], 0, 0, 0);
        }
    }

    if (islast) {
        #pragma unroll
        for (int nf = 0; nf < 4; ++nf) {
            #pragma unroll
            for (int r = 0; r < 4; ++r) {
                const int key = k0 + nf*16 + g*4 + r;
                if (key > qg) S[nf][r] += NEGMASK_L2E;
            }
        }
    }

    // ---- per-lane online softmax (exp2 domain) over 16 local scores ----
    float mx = -INFINITY;
    #pragma unroll
    for (int nf = 0; nf < 4; ++nf)
        #pragma unroll
        for (int r = 0; r < 4; ++r) mx = fmaxf(mx, S[nf][r]);
    mx = fmaxf(mx, __shfl_xor(mx, 16, 64));
    mx = fmaxf(mx, __shfl_xor(mx, 32, 64));
    const float mnew = fmaxf(m_c, mx);
    const float alpha = exp2f(m_c - mnew);
    float sum = 0.0f;
    #pragma unroll
    for (int nf = 0; nf < 4; ++nf)
        #pragma unroll
        for (int r = 0; r < 4; ++r) {
            const float p = exp2f(S[nf][r] - mnew);
            S[nf][r] = p;
            sum += p;
        }
    sum += __shfl_xor(sum, 16, 64);
    sum += __shfl_xor(sum, 32, 64);
    l_c = l_c * alpha + sum;
    m_c = mnew;
    #pragma unroll
    for (int nf = 0; nf < 4; ++nf)
        #pragma unroll
        for (int r = 0; r < 4; ++r) Oacc[nf][r] *= alpha;

    // ---- P^T C-layout -> LDS as P[q][k] (truncation pack, b64 store) ----
    #pragma unroll
    for (int nf = 0; nf < 4; ++nf) {
        uint2v u;
        u[0] = pack_trunc(S[nf][0], S[nf][1]);
        u[1] = pack_trunc(S[nf][2], S[nf][3]);
        *(uint2v*)(Pl + c*72 + nf*16 + g*4) = u;
    }

    // ---- O^T += V^T P : A = V rows (d) from LDS (swizzled), B = P ----
    #pragma unroll
    for (int st = 0; st < 2; ++st) {
        const short8 pf = *(const short8*)(Pl + c * 72 + g*8 + 32*st);
        #pragma unroll
        for (int nf = 0; nf < 4; ++nf) {
            const int row = nf*16 + c;
            const short8 vf = *(const short8*)(Vs + row*HD + (((g + 4*st) ^ (c & 7)) * 8));
            Oacc[nf] = __builtin_amdgcn_mfma_f32_16x16x32_bf16(vf, pf, Oacc[nf], 0, 0, 0);
        }
    }
}

__global__ __launch_bounds__(256) void attn_mfma(
    const unsigned short* __restrict__ Q,   // [B,H,S,HD] bf16 (pre-scaled, exp2 domain)
    const unsigned short* __restrict__ K,   // [B,H,S,HD]
    const unsigned short* __restrict__ VT,  // [B,H,HD,S]
    unsigned short* __restrict__ O)         // [B,S,H*HD] bf16
{
    const int idx = blockIdx.x;             // 0..767
    const int bh  = idx % 48;
    const int z   = 15 - (idx / 48);        // q64-tile, LPT: big z first
    const int q0  = z * 64;

    const unsigned short* Qp  = Q  + (size_t)bh * SS * HD;
    const unsigned short* Kp  = K  + (size_t)bh * SS * HD;
    const unsigned short* VTp = VT + (size_t)bh * HD * SS;

    __shared__ unsigned short Ks[2][64*HD]; // 16 KB
    __shared__ unsigned short Vs[2][64*HD]; // 16 KB
    __shared__ unsigned short Pl[4][16*72]; // 9 KB

    const int t    = threadIdx.x;
    const int w    = t >> 6;
    const int lane = t & 63;
    const int c    = lane & 15;
    const int g    = lane >> 4;
    const int qg   = q0 + w*16 + c;

    short8 qf[2];
    #pragma unroll
    for (int st = 0; st < 2; ++st)
        qf[st] = *(const short8*)(Qp + (size_t)qg * HD + g*8 + 32*st);

    floatx4 Oacc[4] = {};
    float m_c = -INFINITY, l_c = 0.0f;

    const int ntile = z + 1;

    stage_tile(Kp, VTp, 0, w, lane, Ks[0], Vs[0]);
    __syncthreads();

    for (int kt = 0; kt < ntile; ++kt) {
        const int cur = kt & 1;
        if (kt + 1 < ntile)
            stage_tile(Kp, VTp, (kt+1)*64, w, lane, Ks[cur^1], Vs[cur^1]);
        attn_process_tile(Ks[cur], Vs[cur], qf, kt*64, kt == ntile-1,
                          qg, c, g, m_c, l_c, Oacc, Pl[w]);
        if (kt + 1 < ntile)
            __syncthreads();
    }

    // ---- epilogue: normalize, write [B,S,H*HD] bf16 (8B stores) ----
    const int b = bh / NH, h = bh % NH;
    const float inv = 1.0f / l_c;
    unsigned short* op = O + ((size_t)(b*SS + qg))*DM + h*HD;
    #pragma unroll
    for (int nf = 0; nf < 4; ++nf) {
        ushort4v o4;
        #pragma unroll
        for (int r = 0; r < 4; ++r) o4[r] = f2bf(Oacc[nf][r] * inv);
        *(ushort4v*)(op + nf*16 + g*4) = o4;
    }
}

// ---------------------------------------------------------------------------
// Kernel 3: output projection, 128x64 BK=64 single-buffered (R8, verified).
// ---------------------------------------------------------------------------
__global__ __launch_bounds__(256) void out_mfma(
    const unsigned short* __restrict__ A,    // [4096,768] bf16
    const unsigned short* __restrict__ Wb,   // [768,768] bf16
    const float* __restrict__ bias,
    float* __restrict__ outf)
{
    const int n0 = blockIdx.x * 64;
    const int m0 = blockIdx.y * 128;

    __shared__ unsigned short As[128*64];
    __shared__ unsigned short Bs[64*64];

    const int t = threadIdx.x;
    const int w = t >> 6, lane = t & 63;
    const int c = lane & 15, g = lane >> 4;
    const int wr = w >> 1, wc = w & 1;

    floatx4 acc[4][2] = {};

    for (int kt = 0; kt < 12; ++kt) {
        __syncthreads();
        gemm_stage64(A, Wb, m0, n0, kt*64, w, lane, As, Bs);
        __syncthreads();
        gemm_compute64(As, Bs, wr, wc, c, g, acc);
    }

    #pragma unroll
    for (int mi = 0; mi < 4; ++mi) {
        #pragma unroll
        for (int r = 0; r < 4; ++r) {
            const int m = m0 + wr*64 + mi*16 + g*4 + r;
            #pragma unroll
            for (int ni = 0; ni < 2; ++ni) {
                const int n = n0 + wc*32 + ni*16 + c;
                outf[(size_t)m * DM + n] = acc[mi][ni][r] + bias[n];
            }
        }
    }
}

// ---------------------------------------------------------------------------
extern "C" void kernel_launch(void* const* d_in, const int* in_sizes, int n_in,
                              void* d_out, int out_size, void* d_ws, size_t ws_size,
                              hipStream_t stream) {
    const float* X  = (const float*)d_in[0];
    const float* Wq = (const float*)d_in[1];
    const float* bq = (const float*)d_in[2];
    const float* Wk = (const float*)d_in[3];
    const float* bk = (const float*)d_in[4];
    const float* Wv = (const float*)d_in[5];
    const float* bv = (const float*)d_in[6];
    const float* Wo = (const float*)d_in[7];
    const float* bo = (const float*)d_in[8];
    float* out = (float*)d_out;

    const size_t elems = (size_t)MTOT * DM;       // 3,145,728
    const size_t welems = (size_t)DM * DM;        //   589,824
    unsigned short* q    = (unsigned short*)d_ws;
    unsigned short* k    = q    + elems;
    unsigned short* vt   = k    + elems;          // V transposed [B,H,HD,S]
    unsigned short* attn = vt   + elems;
    unsigned short* xb   = attn + elems;
    unsigned short* wqb  = xb   + elems;          // packed W_qkv starts here
    unsigned short* wkb  = wqb  + welems;
    unsigned short* wvb  = wkb  + welems;
    unsigned short* wob  = wvb  + welems;         // total ~36.2 MB

    convert_bf16<<<dim3((XQ4 + 4*WQ4) / 256), 256, 0, stream>>>(
        X, Wq, Wk, Wv, Wo, xb, wqb, wkb, wvb, wob);
    qkv_mfma<<<dim3(36, 32), 256, 0, stream>>>(
        xb, wqb, bq, bk, bv, q, k, vt);
    attn_mfma<<<dim3(768), 256, 0, stream>>>(q, k, vt, attn);
    out_mfma<<<dim3(12, 32), 256, 0, stream>>>(attn, wob, bo, out);
}